// Round 4
// baseline (999.099 us; speedup 1.0000x reference)
//
#include <hip/hip_runtime.h>
#include <math.h>

#define D 256        // embedding dim
#define P 128        // projection dim
#define K 8192       // num embeddings
#define NTOK 16384   // 16*1024 tokens
#define NROWS (NTOK + K)
#define NCHUNK 8
#define KCHUNK (K / NCHUNK)   // 1024 codes per chunk
#define CAP 15               // candidate slots per (token, chunk); record = 16 ints
#define MARGIN 3.0f
#define FLT_BIG 3.402823466e+38f

typedef __attribute__((ext_vector_type(8))) short bf16x8;
typedef __attribute__((ext_vector_type(4))) float f32x4;
typedef __attribute__((ext_vector_type(8))) unsigned short u16x8;

__device__ __forceinline__ unsigned short f32_to_bf16_rne(float f) {
    unsigned int u = __float_as_uint(f);
    u = (u + 0x7fffu + ((u >> 16) & 1u)) >> 16;
    return (unsigned short)u;
}

// ---------------------------------------------------------------------------
// Kernel 1: fused projection of x (rows < NTOK) and codebook (rows >= NTOK).
// Emits fp32 projections + row norms + bf16 copies for the MFMA filter.
// ARITHMETIC ORDER MUST NOT CHANGE (argmin decisions matched numpy with it).
// ---------------------------------------------------------------------------
__global__ __launch_bounds__(256) void proj_kernel(
    const float* __restrict__ x, const float* __restrict__ cb,
    const float* __restrict__ w, const float* __restrict__ bias,
    float* __restrict__ xproj, float* __restrict__ cproj,
    float* __restrict__ xnorm, float* __restrict__ cnorm,
    unsigned short* __restrict__ xh, unsigned short* __restrict__ ch)
{
    __shared__ float As[16][D];   // 16 KB
    const int tid = threadIdx.x;
    const int row0 = blockIdx.x * 16;

    for (int i = tid; i < 16 * (D / 4); i += 256) {
        int r = i / (D / 4);
        int c4 = i % (D / 4);
        int gr = row0 + r;
        const float* src = (gr < NTOK) ? (x + (size_t)gr * D)
                                       : (cb + (size_t)(gr - NTOK) * D);
        float4 v = ((const float4*)src)[c4];
        ((float4*)&As[r][0])[c4] = v;
    }
    __syncthreads();

    const int r = tid >> 4;          // 0..15
    const int c0 = (tid & 15) * 8;   // 0..120

    float acc[8];
#pragma unroll
    for (int j = 0; j < 8; j++) acc[j] = 0.f;

    for (int d = 0; d < D; d += 4) {
        float4 a4 = *(const float4*)&As[r][d];
#pragma unroll
        for (int dd = 0; dd < 4; dd++) {
            float av = (dd == 0) ? a4.x : (dd == 1) ? a4.y : (dd == 2) ? a4.z : a4.w;
            float4 w0 = *(const float4*)&w[(size_t)(d + dd) * P + c0];
            float4 w1 = *(const float4*)&w[(size_t)(d + dd) * P + c0 + 4];
            acc[0] = fmaf(av, w0.x, acc[0]);
            acc[1] = fmaf(av, w0.y, acc[1]);
            acc[2] = fmaf(av, w0.z, acc[2]);
            acc[3] = fmaf(av, w0.w, acc[3]);
            acc[4] = fmaf(av, w1.x, acc[4]);
            acc[5] = fmaf(av, w1.y, acc[5]);
            acc[6] = fmaf(av, w1.z, acc[6]);
            acc[7] = fmaf(av, w1.w, acc[7]);
        }
    }

    float out[8];
    float nrm = 0.f;
    u16x8 hv;
#pragma unroll
    for (int j = 0; j < 8; j++) {
        out[j] = acc[j] + bias[c0 + j];
        nrm = fmaf(out[j], out[j], nrm);
        hv[j] = f32_to_bf16_rne(out[j]);
    }

    const int gr = row0 + r;
    float* dst;
    unsigned short* hdst;
    if (gr < NTOK) { dst = xproj + (size_t)gr * P; hdst = xh + (size_t)gr * P; }
    else           { dst = cproj + (size_t)(gr - NTOK) * P; hdst = ch + (size_t)(gr - NTOK) * P; }
    float4 o0; o0.x = out[0]; o0.y = out[1]; o0.z = out[2]; o0.w = out[3];
    float4 o1; o1.x = out[4]; o1.y = out[5]; o1.z = out[6]; o1.w = out[7];
    *(float4*)&dst[c0] = o0;
    *(float4*)&dst[c0 + 4] = o1;
    *(u16x8*)&hdst[c0] = hv;

#pragma unroll
    for (int off = 1; off < 16; off <<= 1)
        nrm += __shfl_xor(nrm, off, 16);
    if ((tid & 15) == 0) {
        if (gr < NTOK) xnorm[gr] = nrm;
        else           cnorm[gr - NTOK] = nrm;
    }
}

// ---------------------------------------------------------------------------
// Kernel 2: bf16 MFMA distance filter, wave-autonomous.
// Block = 256 thr (4 waves) = 128 tokens x a 1024-code chunk.
// Each wave owns 32 tokens x all 64 codes of a tile: A-fragments live in
// registers (loaded once from global), per-token running min is a pure
// in-wave butterfly (no LDS atomics, 2 barriers/tile for B staging only).
// Candidate semantics identical to round 3 (superset of fp32 argmin).
// ---------------------------------------------------------------------------
__global__ __launch_bounds__(256) void filter_kernel(
    const unsigned short* __restrict__ xh, const unsigned short* __restrict__ ch,
    const float* __restrict__ xnorm, const float* __restrict__ cnorm,
    float* __restrict__ chunkmin, int* __restrict__ cand)
{
    __shared__ short sb[64][136];     // codes x P, pad +8 (17.4 KB)
    __shared__ float smin[128];
    __shared__ int scnt[128];
    __shared__ int scand[128][CAP];

    const int tid = threadIdx.x;
    const int tok0 = blockIdx.x * 128;
    const int chunk = blockIdx.y;
    const int k0 = chunk * KCHUNK;

    const int wave = tid >> 6;      // 0..3 -> token group of 32
    const int lane = tid & 63;
    const int quad = lane >> 4;     // 0..3
    const int l15 = lane & 15;

    if (tid < 128) scnt[tid] = 0;

    // A fragments in registers: token rows (wave*32 + mi*16 + l15), k = ks*32+quad*8.
    bf16x8 afrag[2][4];
#pragma unroll
    for (int mi = 0; mi < 2; mi++)
#pragma unroll
        for (int ks = 0; ks < 4; ks++)
            afrag[mi][ks] = *(const bf16x8*)(
                xh + (size_t)(tok0 + wave * 32 + mi * 16 + l15) * P + ks * 32 + quad * 8);

    // xnorm for this lane's 8 token slots (token = wave*32 + mi*16 + quad*4 + r).
    float xnv[2][4];
#pragma unroll
    for (int mi = 0; mi < 2; mi++)
#pragma unroll
        for (int r = 0; r < 4; r++)
            xnv[mi][r] = xnorm[tok0 + wave * 32 + mi * 16 + quad * 4 + r];

    float rmin[2][4];
#pragma unroll
    for (int mi = 0; mi < 2; mi++)
#pragma unroll
        for (int r = 0; r < 4; r++) rmin[mi][r] = FLT_BIG;

    for (int ct = 0; ct < KCHUNK / 64; ct++) {
        const int kt = k0 + ct * 64;
        __syncthreads();   // prior tile fully consumed
        for (int i = tid; i < 64 * 16; i += 256) {
            int row = i >> 4;
            int c8 = i & 15;
            uint4 v = *(const uint4*)(ch + (size_t)(kt + row) * P + c8 * 8);
            *(uint4*)&sb[row][c8 * 8] = v;
        }
        __syncthreads();

        f32x4 acc[2][4];   // mi x nj
#pragma unroll
        for (int mi = 0; mi < 2; mi++)
#pragma unroll
            for (int nj = 0; nj < 4; nj++)
                acc[mi][nj] = (f32x4)(0.f);

#pragma unroll
        for (int ks = 0; ks < 4; ks++) {
            const int kf = ks * 32 + quad * 8;
            bf16x8 b0 = *(const bf16x8*)&sb[l15][kf];
            bf16x8 b1 = *(const bf16x8*)&sb[16 + l15][kf];
            bf16x8 b2 = *(const bf16x8*)&sb[32 + l15][kf];
            bf16x8 b3 = *(const bf16x8*)&sb[48 + l15][kf];
            acc[0][0] = __builtin_amdgcn_mfma_f32_16x16x32_bf16(afrag[0][ks], b0, acc[0][0], 0, 0, 0);
            acc[0][1] = __builtin_amdgcn_mfma_f32_16x16x32_bf16(afrag[0][ks], b1, acc[0][1], 0, 0, 0);
            acc[0][2] = __builtin_amdgcn_mfma_f32_16x16x32_bf16(afrag[0][ks], b2, acc[0][2], 0, 0, 0);
            acc[0][3] = __builtin_amdgcn_mfma_f32_16x16x32_bf16(afrag[0][ks], b3, acc[0][3], 0, 0, 0);
            acc[1][0] = __builtin_amdgcn_mfma_f32_16x16x32_bf16(afrag[1][ks], b0, acc[1][0], 0, 0, 0);
            acc[1][1] = __builtin_amdgcn_mfma_f32_16x16x32_bf16(afrag[1][ks], b1, acc[1][1], 0, 0, 0);
            acc[1][2] = __builtin_amdgcn_mfma_f32_16x16x32_bf16(afrag[1][ks], b2, acc[1][2], 0, 0, 0);
            acc[1][3] = __builtin_amdgcn_mfma_f32_16x16x32_bf16(afrag[1][ks], b3, acc[1][3], 0, 0, 0);
        }

        // code = kt + nj*16 + l15 ; token = tok0 + wave*32 + mi*16 + quad*4 + r
        float cn[4];
#pragma unroll
        for (int nj = 0; nj < 4; nj++) cn[nj] = cnorm[kt + nj * 16 + l15];

#pragma unroll
        for (int mi = 0; mi < 2; mi++)
#pragma unroll
            for (int r = 0; r < 4; r++) {
                float d[4];
#pragma unroll
                for (int nj = 0; nj < 4; nj++)
                    d[nj] = (xnv[mi][r] - 2.0f * acc[mi][nj][r]) + cn[nj];
                float m = fminf(fminf(d[0], d[1]), fminf(d[2], d[3]));
                // butterfly over the 16 lanes of this quad-group (offsets <16
                // stay within the group under the wave-wide default width)
#pragma unroll
                for (int off = 1; off < 16; off <<= 1)
                    m = fminf(m, __shfl_xor(m, off));
                float rm = fminf(rmin[mi][r], m);
                rmin[mi][r] = rm;
                float thr = rm + MARGIN;
                int tl = wave * 32 + mi * 16 + quad * 4 + r;
#pragma unroll
                for (int nj = 0; nj < 4; nj++) {
                    if (d[nj] <= thr) {
                        int pos = atomicAdd(&scnt[tl], 1);
                        if (pos < CAP)
                            scand[tl][pos] = kt + nj * 16 + l15;
                    }
                }
            }
    }

    // publish per-token chunk minima (all 16 lanes of a group hold rmin; use l15==0)
    if (l15 == 0) {
#pragma unroll
        for (int mi = 0; mi < 2; mi++)
#pragma unroll
            for (int r = 0; r < 4; r++)
                smin[wave * 32 + mi * 16 + quad * 4 + r] = rmin[mi][r];
    }
    __syncthreads();

    if (tid < 128) {
        int t = tok0 + tid;
        int cnt = scnt[tid];
        if (cnt > CAP) cnt = CAP;
        int* rec = cand + ((size_t)t * NCHUNK + chunk) * (CAP + 1);
        rec[0] = cnt;
        for (int j = 0; j < cnt; j++) rec[1 + j] = scand[tid][j];
        chunkmin[(size_t)t * NCHUNK + chunk] = smin[tid];
    }
}

// ---------------------------------------------------------------------------
// Kernel 3: exact fp32 rescore of candidates. One wave per token.
// Same serial-fma arithmetic/order as round 1 (matched numpy).
// ---------------------------------------------------------------------------
__global__ __launch_bounds__(256) void rescore_kernel(
    const float* __restrict__ xproj, const float* __restrict__ cproj,
    const float* __restrict__ xnorm, const float* __restrict__ cnorm,
    const float* __restrict__ chunkmin, const int* __restrict__ cand,
    int* __restrict__ fidx)
{
    const int tid = threadIdx.x;
    const int lane = tid & 63;
    const int wave = tid >> 6;
    const int t = blockIdx.x * 4 + wave;

    // global approx min over chunk minima (lanes 0..7 hold the 8 chunk minima)
    float cm = (lane < NCHUNK) ? chunkmin[(size_t)t * NCHUNK + lane] : FLT_BIG;
#pragma unroll
    for (int off = 1; off < 8; off <<= 1)
        cm = fminf(cm, __shfl_xor(cm, off));
    float mg = __shfl(cm, 0);   // wave-relative lane 0 has the min

    const float xn = xnorm[t];
    float bv = FLT_BIG;
    int bi = 0x7fffffff;

    for (int c = 0; c < NCHUNK; c++) {
        if (chunkmin[(size_t)t * NCHUNK + c] > mg + MARGIN) continue;
        const int* rec = cand + ((size_t)t * NCHUNK + c) * (CAP + 1);
        int cnt = rec[0];
        for (int j = 0; j < cnt; j++) {
            if (((c * CAP + j) & 63) != lane) continue;
            int k = rec[1 + j];
            const float* xr = xproj + (size_t)t * P;
            const float* cr = cproj + (size_t)k * P;
            float s = 0.f;
            for (int p = 0; p < P; p += 4) {
                float4 a = *(const float4*)&xr[p];
                float4 b = *(const float4*)&cr[p];
                s = fmaf(a.x, b.x, s);
                s = fmaf(a.y, b.y, s);
                s = fmaf(a.z, b.z, s);
                s = fmaf(a.w, b.w, s);
            }
            float dist = (xn - 2.0f * s) + cnorm[k];
            if (dist < bv || (dist == bv && k < bi)) { bv = dist; bi = k; }
        }
    }

    // wave (val, idx) argmin reduce, tie -> lower index
#pragma unroll
    for (int off = 1; off < 64; off <<= 1) {
        float ov = __shfl_xor(bv, off);
        int oi = __shfl_xor(bi, off);
        if (ov < bv || (ov == bv && oi < bi)) { bv = ov; bi = oi; }
    }
    if (lane == 0) fidx[t] = bi;
}

// ---------------------------------------------------------------------------
// Kernel 4: write the full one-hot rows (fused zero-fill) + gather codebook.
// Block = 256 thr handles 8 tokens. Grid: NTOK/8 = 2048 blocks.
// ---------------------------------------------------------------------------
__global__ __launch_bounds__(256) void output_kernel(
    const int* __restrict__ fidx, const float* __restrict__ cb,
    float* __restrict__ discrete, float* __restrict__ quant)
{
    __shared__ int sidx[8];
    const int tid = threadIdx.x;
    const int tok0 = blockIdx.x * 8;
    if (tid < 8) sidx[tid] = fidx[tok0 + tid];
    __syncthreads();

    // one-hot rows: 8 tokens x 2048 float4 (native vec type for nontemporal)
    for (int i = tid; i < 8 * (K / 4); i += 256) {
        int tl = i >> 11;
        int f4 = i & 2047;
        int id = sidx[tl];
        f32x4 v = (f32x4)(0.f);
        if (f4 == (id >> 2)) v[id & 3] = 1.f;
        __builtin_nontemporal_store(v, (f32x4*)(discrete + (size_t)(tok0 + tl) * K + f4 * 4));
    }

    // quantized rows: 8 tokens x 64 float4
    for (int i = tid; i < 8 * (D / 4); i += 256) {
        int tl = i >> 6;
        int c4 = i & 63;
        float4 v = ((const float4*)(cb + (size_t)sidx[tl] * D))[c4];
        ((float4*)(quant + (size_t)(tok0 + tl) * D))[c4] = v;
    }
}

// ---------------------------------------------------------------------------
extern "C" void kernel_launch(void* const* d_in, const int* in_sizes, int n_in,
                              void* d_out, int out_size, void* d_ws, size_t ws_size,
                              hipStream_t stream) {
    const float* x    = (const float*)d_in[0];   // [16,1024,256]
    const float* cb   = (const float*)d_in[1];   // [8192,256]
    const float* w    = (const float*)d_in[2];   // [256,128]
    const float* bias = (const float*)d_in[3];   // [128]

    float* out = (float*)d_out;
    float* discrete = out;                               // [16384, 8192]
    float* quant = out + (size_t)NTOK * K;               // [16384, 256]

    char* ws = (char*)d_ws;
    size_t off = 0;
    float* xproj = (float*)(ws + off); off += (size_t)NTOK * P * 4;
    float* cproj = (float*)(ws + off); off += (size_t)K * P * 4;
    float* xnorm = (float*)(ws + off); off += (size_t)NTOK * 4;
    float* cnorm = (float*)(ws + off); off += (size_t)K * 4;
    unsigned short* xh = (unsigned short*)(ws + off); off += (size_t)NTOK * P * 2;
    unsigned short* ch = (unsigned short*)(ws + off); off += (size_t)K * P * 2;
    float* chunkmin = (float*)(ws + off); off += (size_t)NTOK * NCHUNK * 4;
    int* cand = (int*)(ws + off); off += (size_t)NTOK * NCHUNK * (CAP + 1) * 4;
    int* fidx = (int*)(ws + off); off += (size_t)NTOK * 4;

    proj_kernel<<<dim3(NROWS / 16), dim3(256), 0, stream>>>(
        x, cb, w, bias, xproj, cproj, xnorm, cnorm, xh, ch);

    filter_kernel<<<dim3(NTOK / 128, NCHUNK), dim3(256), 0, stream>>>(
        xh, ch, xnorm, cnorm, chunkmin, cand);

    rescore_kernel<<<dim3(NTOK / 4), dim3(256), 0, stream>>>(
        xproj, cproj, xnorm, cnorm, chunkmin, cand, fidx);

    output_kernel<<<dim3(NTOK / 8), dim3(256), 0, stream>>>(
        fidx, cb, discrete, quant);
}